// Round 4
// baseline (606.309 us; speedup 1.0000x reference)
//
#include <hip/hip_runtime.h>
#include <stdint.h>

constexpr int C = 128;
constexpr int F1 = 192;  // C + HID

// ---------------- edge dtype detection ----------------
// If edge_index is true int64 (LE), every odd 4-byte word in the first 2E words
// is a high half of a value < 2^31 => 0. If int32, those words are random node
// ids; finding any nonzero proves int32. res[5] = 1 iff int32 layout.
__global__ void k_detect(const int* __restrict__ ei, int E, int* __restrict__ res) {
    int t = blockIdx.x * 256 + threadIdx.x;
    int idx = 2 * t + 1;                 // odd word; t < 4096 <= E so in bounds
    if (idx < 2 * E && ei[idx] != 0) atomicOr(&res[5], 1);
}

// ---------------- degree ----------------
__global__ void k_deg(const int* __restrict__ ei, int E, const int* __restrict__ res,
                      int* __restrict__ outdeg, int* __restrict__ indeg) {
    int e = blockIdx.x * 256 + threadIdx.x;
    if (e < E) {
        bool i64 = (res[5] == 0);
        int s = i64 ? ei[2 * e]       : ei[e];
        int d = i64 ? ei[2 * (E + e)] : ei[E + e];
        atomicAdd(&outdeg[s], 1);
        atomicAdd(&indeg[d], 1);
    }
}

// ---------------- exclusive scan (3-kernel), with optional fused norm ----------------
__global__ void scan1(const int* __restrict__ in, int* __restrict__ out,
                      int* __restrict__ bsums, int n,
                      const int* __restrict__ outdeg, float* __restrict__ nsrc,
                      float* __restrict__ ndst) {
    __shared__ int sh[1024];
    int i = blockIdx.x * 1024 + threadIdx.x;
    int v = (i < n) ? in[i] : 0;
    // fused degree->norm (first scan only; in == indeg there)
    if (nsrc && i < n) {
        int od = outdeg[i]; if (od < 1) od = 1;
        int id = v;         if (id < 1) id = 1;
        nsrc[i] = (float)(1.0 / sqrt((double)od));
        ndst[i] = (float)(1.0 / sqrt((double)id));
    }
    sh[threadIdx.x] = v;
    __syncthreads();
    for (int off = 1; off < 1024; off <<= 1) {
        int t = (threadIdx.x >= off) ? sh[threadIdx.x - off] : 0;
        __syncthreads();
        sh[threadIdx.x] += t;
        __syncthreads();
    }
    if (i < n) out[i] = sh[threadIdx.x] - v;   // exclusive
    if (threadIdx.x == 1023) bsums[blockIdx.x] = sh[1023];
}

__global__ void scan2(int* __restrict__ bsums, int nb) {
    __shared__ int sh[1024];
    int t = threadIdx.x;
    int v = (t < nb) ? bsums[t] : 0;
    sh[t] = v;
    __syncthreads();
    for (int off = 1; off < 1024; off <<= 1) {
        int u = (t >= off) ? sh[t - off] : 0;
        __syncthreads();
        sh[t] += u;
        __syncthreads();
    }
    if (t < nb) bsums[t] = sh[t] - v;          // exclusive block offsets
}

__global__ void scan3(int* __restrict__ data, const int* __restrict__ bsums,
                      int* __restrict__ copy2, int n) {
    int i = blockIdx.x * 1024 + threadIdx.x;
    if (i < n) {
        int v = data[i] + bsums[blockIdx.x];
        data[i] = v;
        if (copy2) copy2[i] = v;
    }
}

// ---------------- CSR build (by dst) ----------------
__global__ void k_csr(const int* __restrict__ ei, int E, const int* __restrict__ res,
                      int* __restrict__ cursor, int* __restrict__ csr) {
    int e = blockIdx.x * 256 + threadIdx.x;
    if (e < E) {
        bool i64 = (res[5] == 0);
        int s = i64 ? ei[2 * e]       : ei[e];
        int d = i64 ? ei[2 * (E + e)] : ei[E + e];
        int p = atomicAdd(&cursor[d], 1);
        csr[p] = s;
    }
}

// ---------------- layer-1 aggregation: one wave per node ----------------
// g[n][:] = ndst[n] * sum_{s in sorted in-neighbors} x[s][:]*nsrc[s]
// Neighbor list is sorted in-wave and written back so every replay sums in
// identical order -> deterministic scores -> stable top-k boundary.
// deg is wave-uniform (one node per wave), so the rank loop runs deg (not 64)
// iterations: pad lanes (v=INT_MAX) all get rank==deg and collide on a lane
// we never read. Broadcasts use readlane (SALU) instead of ds_bpermute.
__global__ __launch_bounds__(256) void k_agg(const float* __restrict__ x,
        int* __restrict__ csr, const int* __restrict__ indeg,
        const int* __restrict__ offsets, const float* __restrict__ nsrc,
        const float* __restrict__ ndst, float* __restrict__ g, int N) {
    int wid  = (blockIdx.x * 256 + threadIdx.x) >> 6;  // node id (wave-uniform)
    int lane = threadIdx.x & 63;
    if (wid >= N) return;
    int deg = indeg[wid];
    int off = offsets[wid];
    float acc0 = 0.f, acc1 = 0.f;
    if (deg > 0 && deg <= 64) {
        int v = (lane < deg) ? csr[off + lane] : 0x7fffffff;
        int rank = 0;
        for (int j = 0; j < deg; ++j) {                  // deg iters, not 64
            int vj = __builtin_amdgcn_readlane(v, j);    // SGPR broadcast
            rank += (vj < v) || (vj == v && j < lane);
        }
        int sv = __builtin_amdgcn_ds_permute(rank << 2, v);  // push v to lane 'rank'
        if (lane < deg) csr[off + lane] = sv;                // sorted write-back for k_l2
        float nsv = (lane < deg) ? nsrc[sv] : 0.f;           // prefetch all norms
        int nsb = __float_as_int(nsv);
        for (int i = 0; i < deg; ++i) {
            int s    = __builtin_amdgcn_readlane(sv, i);               // SGPR
            float ns = __int_as_float(__builtin_amdgcn_readlane(nsb, i));
            float2 xr = ((const float2*)x)[(size_t)s * 64 + lane];     // 512B coalesced
            acc0 = fmaf(xr.x, ns, acc0);
            acc1 = fmaf(xr.y, ns, acc1);
        }
    } else if (deg > 64) {   // Poisson(8) tail: ~impossible; correct, unsorted
        for (int i = 0; i < deg; ++i) {
            int s = csr[off + i];
            float ns = nsrc[s];
            float2 xr = ((const float2*)x)[(size_t)s * 64 + lane];
            acc0 = fmaf(xr.x, ns, acc0);
            acc1 = fmaf(xr.y, ns, acc1);
        }
    }
    float nd = ndst[wid];
    ((float2*)g)[(size_t)wid * 64 + lane] = make_float2(acc0 * nd, acc1 * nd);
}

// ---------------- fused GEMM + ReLU + dot(W2): thread per node ----------------
// tn[n] = nsrc[n] * sum_j relu(b1[j] + sum_c g[n][c]*W1[c][j]) * W2[j]
// W1/b1/W2 are read with wave-uniform indices from global memory: uniformity
// analysis + __restrict__ turns these into s_load through the scalar cache
// (SGPR operands to v_fma). No LDS, no __syncthreads, LDS pipe idle.
__global__ __launch_bounds__(256) void k_gemm(const float* __restrict__ g,
        const float* __restrict__ W1, const float* __restrict__ b1,
        const float* __restrict__ W2, const float* __restrict__ nsrc,
        float* __restrict__ tn, int N) {
    int n = blockIdx.x * 256 + threadIdx.x;
    if (n >= N) return;
    float r[128];
    const float4* gr = (const float4*)(g + (size_t)n * 128);
    #pragma unroll
    for (int q = 0; q < 32; ++q) {
        float4 v = gr[q];
        r[4*q+0] = v.x; r[4*q+1] = v.y; r[4*q+2] = v.z; r[4*q+3] = v.w;
    }
    float t = 0.f;
    #pragma unroll 1
    for (int jj = 0; jj < 48; ++jj) {                    // 192 outputs / 4
        const float4* Wc = (const float4*)(W1 + jj * 4); // row-major [128][192]
        float a0 = b1[jj*4+0], a1 = b1[jj*4+1], a2 = b1[jj*4+2], a3 = b1[jj*4+3];
        #pragma unroll
        for (int c = 0; c < 128; ++c) {
            float4 w = Wc[c * 48];                       // uniform -> s_load_dwordx4
            a0 = fmaf(r[c], w.x, a0);
            a1 = fmaf(r[c], w.y, a1);
            a2 = fmaf(r[c], w.z, a2);
            a3 = fmaf(r[c], w.w, a3);
        }
        t += fmaxf(a0, 0.f) * W2[jj*4+0] + fmaxf(a1, 0.f) * W2[jj*4+1]
           + fmaxf(a2, 0.f) * W2[jj*4+2] + fmaxf(a3, 0.f) * W2[jj*4+3];
    }
    tn[n] = t * nsrc[n];
}

// ---------------- layer-2 scalar aggregation + |score| bits + histogram ----------------
// W2 commutes past the aggregation: per-edge payload is ONE float, not 192.
__global__ void k_l2(const int* __restrict__ csr, const int* __restrict__ indeg,
                     const int* __restrict__ offsets, const float* __restrict__ tn,
                     const float* __restrict__ ndst, const float* __restrict__ b2,
                     unsigned int* __restrict__ U, int* __restrict__ hist1, int N) {
    int n = blockIdx.x * 256 + threadIdx.x;
    if (n >= N) return;
    int deg = indeg[n], off = offsets[n];
    float s = 0.f;
    for (int i = 0; i < deg; ++i) s += tn[csr[off + i]];   // sorted order -> deterministic
    float sc = ndst[n] * s + b2[0];
    unsigned int u = __float_as_uint(fabsf(sc));           // monotonic for non-negative floats
    U[n] = u;
    atomicAdd(&hist1[u >> 16], 1);
}

// ---------------- radix-select pass 1: high 16 bits ----------------
__global__ void k_findbin1(const int* __restrict__ hist, int k, int* __restrict__ res) {
    __shared__ int sh[1024];
    int t = threadIdx.x;
    int base = 65535 - 64 * t;      // chunk t covers 64 bins, high->low
    int s = 0;
    for (int q = 0; q < 64; ++q) s += hist[base - q];
    sh[t] = s;
    __syncthreads();
    int v = s;
    for (int off = 1; off < 1024; off <<= 1) {
        int u = (t >= off) ? sh[t - off] : 0;
        __syncthreads();
        sh[t] += u;
        __syncthreads();
    }
    int before = sh[t] - v;          // elements in all bins above this chunk
    if (before < k && sh[t] >= k) {
        int cum = before;
        for (int q = 0; q < 64; ++q) {
            int b = base - q;
            int h = hist[b];
            if (cum + h >= k) { res[0] = b; res[1] = k - cum; break; }
            cum += h;
        }
    }
}

__global__ void k_hist2(const unsigned int* __restrict__ U, const int* __restrict__ res,
                        int* __restrict__ hist2, int N) {
    int n = blockIdx.x * 256 + threadIdx.x;
    if (n < N) {
        unsigned int u = U[n];
        if ((int)(u >> 16) == res[0]) atomicAdd(&hist2[u & 0xffff], 1);
    }
}

// ---------------- radix-select pass 2: low 16 bits ----------------
__global__ void k_findbin2(const int* __restrict__ hist, int* __restrict__ res) {
    __shared__ int sh[1024];
    int k = res[1];
    int t = threadIdx.x;
    int base = 65535 - 64 * t;
    int s = 0;
    for (int q = 0; q < 64; ++q) s += hist[base - q];
    sh[t] = s;
    __syncthreads();
    int v = s;
    for (int off = 1; off < 1024; off <<= 1) {
        int u = (t >= off) ? sh[t - off] : 0;
        __syncthreads();
        sh[t] += u;
        __syncthreads();
    }
    int before = sh[t] - v;
    if (before < k && sh[t] >= k) {
        int cum = before;
        for (int q = 0; q < 64; ++q) {
            int b = base - q;
            int h = hist[b];
            if (cum + h >= k) {
                res[2] = (int)(((unsigned int)res[0] << 16) | (unsigned int)b);  // threshold bits
                res[3] = k - cum;                                                // # ties to keep
                break;
            }
            cum += h;
        }
    }
}

// ---------------- selection flags (+ tie collection) ----------------
__global__ void k_flags(const unsigned int* __restrict__ U, int* __restrict__ res,
                        int* __restrict__ sel, int* __restrict__ tielist, int N) {
    int n = blockIdx.x * 256 + threadIdx.x;
    if (n >= N) return;
    unsigned int T = (unsigned int)res[2];
    unsigned int u = U[n];
    sel[n] = (u > T) ? 1 : 0;
    if (u == T) {
        int p = atomicAdd(&res[4], 1);
        if (p < 4096) tielist[p] = n;
    }
}

// ties: keep the res[3] ties with smallest node index (jax top_k stability:
// equal values ranked by ascending index)
__global__ void k_ties(const int* __restrict__ res, int* __restrict__ tielist,
                       int* __restrict__ sel) {
    if (threadIdx.x != 0) return;
    int cnt = res[4]; if (cnt > 4096) cnt = 4096;
    int need = res[3]; if (need > cnt) need = cnt;
    for (int r = 0; r < need; ++r) {
        int mi = 0, mv = 0x7fffffff;
        for (int i = 0; i < cnt; ++i) {
            int v = tielist[i];
            if (v < mv) { mv = v; mi = i; }
        }
        sel[mv] = 1;
        tielist[mi] = 0x7fffffff;
    }
}

// ---------------- compact rows: one wave per node ----------------
__global__ __launch_bounds__(256) void k_out(const float* __restrict__ x,
        const int* __restrict__ sel, const int* __restrict__ pos,
        float* __restrict__ out, int N) {
    int wid  = (blockIdx.x * 256 + threadIdx.x) >> 6;
    int lane = threadIdx.x & 63;
    if (wid >= N) return;
    if (sel[wid]) {
        int p = pos[wid];
        ((float2*)out)[(size_t)p * 64 + lane] = ((const float2*)x)[(size_t)wid * 64 + lane];
    }
}

extern "C" void kernel_launch(void* const* d_in, const int* in_sizes, int n_in,
                              void* d_out, int out_size, void* d_ws, size_t ws_size,
                              hipStream_t stream) {
    const float* x  = (const float*)d_in[0];
    const int*   ei = (const int*)d_in[1];
    const float* W1 = (const float*)d_in[2];
    const float* b1 = (const float*)d_in[3];
    const float* W2 = (const float*)d_in[4];
    const float* b2 = (const float*)d_in[5];
    int N = in_sizes[0] / C;            // 100000
    int E = in_sizes[1] / 2;            // 800000 (element count, dtype-independent)
    int k = out_size / C;               // harness-derived k: exact, no float repro risk

    char* w = (char*)d_ws;
    size_t ofs = 0;
    auto alloc = [&](size_t bytes) -> char* {
        char* p = w + ofs;
        ofs += (bytes + 511) & ~(size_t)511;
        return p;
    };
    // zero-init region first (single contiguous memset)
    int*   outdeg  = (int*)alloc((size_t)N * 4);
    int*   indeg   = (int*)alloc((size_t)N * 4);
    int*   hist1   = (int*)alloc(65536 * 4);
    int*   hist2   = (int*)alloc(65536 * 4);
    int*   res     = (int*)alloc(64);
    size_t zero_bytes = ofs;
    // rest (fully overwritten before use)
    int*   offsets = (int*)alloc((size_t)(N + 1) * 4);
    int*   cursor  = (int*)alloc((size_t)N * 4);
    int*   csr     = (int*)alloc((size_t)E * 4);
    float* nsrc    = (float*)alloc((size_t)N * 4);
    float* ndst    = (float*)alloc((size_t)N * 4);
    float* g       = (float*)alloc((size_t)N * C * 4);
    float* tn      = (float*)alloc((size_t)N * 4);
    unsigned int* U = (unsigned int*)alloc((size_t)N * 4);
    int*   tielist = (int*)alloc(4096 * 4);
    int*   sel     = (int*)alloc((size_t)N * 4);
    int*   pos     = (int*)alloc((size_t)N * 4);
    int*   bsums   = (int*)alloc(1024 * 4);

    hipMemsetAsync(d_ws, 0, zero_bytes, stream);

    int nb = (N + 1023) / 1024;
    k_detect<<<16, 256, 0, stream>>>(ei, E, res);
    k_deg<<<(E + 255) / 256, 256, 0, stream>>>(ei, E, res, outdeg, indeg);
    scan1<<<nb, 1024, 0, stream>>>(indeg, offsets, bsums, N, outdeg, nsrc, ndst);
    scan2<<<1, 1024, 0, stream>>>(bsums, nb);
    scan3<<<nb, 1024, 0, stream>>>(offsets, bsums, cursor, N);
    k_csr<<<(E + 255) / 256, 256, 0, stream>>>(ei, E, res, cursor, csr);
    k_agg<<<(N + 3) / 4, 256, 0, stream>>>(x, csr, indeg, offsets, nsrc, ndst, g, N);
    k_gemm<<<(N + 255) / 256, 256, 0, stream>>>(g, W1, b1, W2, nsrc, tn, N);
    k_l2<<<(N + 255) / 256, 256, 0, stream>>>(csr, indeg, offsets, tn, ndst, b2, U, hist1, N);
    k_findbin1<<<1, 1024, 0, stream>>>(hist1, k, res);
    k_hist2<<<(N + 255) / 256, 256, 0, stream>>>(U, res, hist2, N);
    k_findbin2<<<1, 1024, 0, stream>>>(hist2, res);
    k_flags<<<(N + 255) / 256, 256, 0, stream>>>(U, res, sel, tielist, N);
    k_ties<<<1, 64, 0, stream>>>(res, tielist, sel);
    scan1<<<nb, 1024, 0, stream>>>(sel, pos, bsums, N, nullptr, nullptr, nullptr);
    scan2<<<1, 1024, 0, stream>>>(bsums, nb);
    scan3<<<nb, 1024, 0, stream>>>(pos, bsums, nullptr, N);
    k_out<<<(N + 3) / 4, 256, 0, stream>>>(x, sel, pos, (float*)d_out, N);
}